// Round 11
// baseline (95.909 us; speedup 1.0000x reference)
//
#include <hip/hip_runtime.h>

#define BATCH 512
#define SEQ   512
#define VOCAB 1000
#define EMB   100
#define UNITS 64
#define SC    2.88539008177792681f   // 2*log2(e): exp2(SC*s) == e^{2s}

typedef float    v2f   __attribute__((ext_vector_type(2)));
typedef unsigned u32x2 __attribute__((ext_vector_type(2)));

// ---------------------------------------------------------------------------
// Kernel 1: P[v][u] = SC*( (emb[v]@Wxh)[u] + b[u] + colsum(Whh)[u] )
// colsum fold supports the r-recurrence: y = x + W.h, h = 1-2r
//   =>  y = (x + W.1) - 2*W.r  -- no per-step h reconstruction in the scan.
// ---------------------------------------------------------------------------
__global__ __launch_bounds__(64) void proj_kernel(
    const float* __restrict__ emb, const float* __restrict__ Wxh,
    const float* __restrict__ bias, const float* __restrict__ Whh,
    float* __restrict__ P) {
  const int v = blockIdx.x;
  const int u = threadIdx.x;
  const float* e = emb + v * EMB;
  float acc = bias[u];
#pragma unroll 5
  for (int d = 0; d < EMB; ++d) acc += e[d] * Wxh[d * UNITS + u];
  float csum = 0.f;
#pragma unroll 8
  for (int i = 0; i < UNITS; ++i) csum += Whh[i * UNITS + u];
  P[v * UNITS + u] = SC * (acc + csum);
}

// ---------------------------------------------------------------------------
// DPP all-gather across the lane's own 16-lane row; slot->source permutation
// calibrated at runtime on lane_id and folded into the weight layout.
// ---------------------------------------------------------------------------
#define DPP_I(src, ctrl) __builtin_amdgcn_update_dpp(0, (src), (ctrl), 0xF, 0xF, true)

#define GATHER_ROW(v_, g_)                                          \
  do {                                                              \
    g_[0] = DPP_I((v_), 0x00);  g_[1] = DPP_I((v_), 0x55);          \
    g_[2] = DPP_I((v_), 0xAA);  g_[3] = DPP_I((v_), 0xFF);          \
    g_[4]  = DPP_I(g_[0], 0x124); g_[5]  = DPP_I(g_[1], 0x124);     \
    g_[6]  = DPP_I(g_[2], 0x124); g_[7]  = DPP_I(g_[3], 0x124);     \
    g_[8]  = DPP_I(g_[0], 0x128); g_[9]  = DPP_I(g_[1], 0x128);     \
    g_[10] = DPP_I(g_[2], 0x128); g_[11] = DPP_I(g_[3], 0x128);     \
    g_[12] = DPP_I(g_[0], 0x12C); g_[13] = DPP_I(g_[1], 0x12C);     \
    g_[14] = DPP_I(g_[2], 0x12C); g_[15] = DPP_I(g_[3], 0x12C);     \
  } while (0)

// Raw permlane swap returning BOTH outputs. Builtin path (scheduler-managed
// hazards, no volatile fence); fallback = r5-proven non-volatile asm.
#if __has_builtin(__builtin_amdgcn_permlane16_swap) && \
    __has_builtin(__builtin_amdgcn_permlane32_swap)
__device__ __forceinline__ u32x2 plswap16(unsigned x, unsigned y) {
  return __builtin_amdgcn_permlane16_swap(x, y, false, false);
}
__device__ __forceinline__ u32x2 plswap32(unsigned x, unsigned y) {
  return __builtin_amdgcn_permlane32_swap(x, y, false, false);
}
#else
__device__ __forceinline__ u32x2 plswap16(unsigned x, unsigned y) {
  asm("s_nop 1\n\tv_permlane16_swap_b32 %0, %1" : "+v"(x), "+v"(y));
  u32x2 r; r.x = x; r.y = y; return r;
}
__device__ __forceinline__ u32x2 plswap32(unsigned x, unsigned y) {
  asm("s_nop 1\n\tv_permlane32_swap_b32 %0, %1" : "+v"(x), "+v"(y));
  u32x2 r; r.x = x; r.y = y; return r;
}
#endif

// Selection-free combine (r5/r10-proven algebra): sum of both swap outputs =
// q_w[l] + q_w[l^N], with the "winning" partial w alternating by lane
// parity -- absorbed into the calibrated weight-column layout below.
__device__ __forceinline__ float swadd16(float vd, float vs) {
  u32x2 p = plswap16((unsigned)__float_as_int(vd), (unsigned)__float_as_int(vs));
  return __int_as_float((int)p.x) + __int_as_float((int)p.y);
}
__device__ __forceinline__ float swadd32(float vd, float vs) {
  u32x2 p = plswap32((unsigned)__float_as_int(vd), (unsigned)__float_as_int(vs));
  return __int_as_float((int)p.x) + __int_as_float((int)p.y);
}

// ---------------------------------------------------------------------------
// Kernel 2: sequential scan on r(t) = 1/(e^{2s}+1), one row per wave.
// Regime (r10-calibrated): latency-bound on the per-step dependency chain
// (~30 links x 5-15 cyc exposed each), issue underneath (VALUBusy 30%).
// This round cuts the longest block: 8-deep pk_fma chains -> 4-deep A/B
// pairs + pk_add merge (r4-proven structure): fma-block links 9 -> 6.
// Chain per step: gather(2) -> pk_fma(4) -> merge(1) -> extract(1) ->
// combine(perm,add,perm,add: 4... 3 levels = 6) -> +a(1) -> exp2/add/rcp(3).
// ---------------------------------------------------------------------------
__global__ __launch_bounds__(64)
__attribute__((amdgpu_waves_per_eu(1, 1)))
void scan_kernel(
    const int* __restrict__ tok, const float* __restrict__ P,
    const float* __restrict__ Whh, const float* __restrict__ Wout,
    const float* __restrict__ bout, float* __restrict__ out) {
  const int row  = blockIdx.x;
  const int lane = threadIdx.x;

  // ---- calibration: gather permutation ----
  int gcal[16];
  GATHER_ROW(lane, gcal);  // gcal[s] = source lane (== unit index) of slot s

  // ---- calibration: swap convention flags F16/F32 (r5-proven probe) ----
  u32x2 pr16 = plswap16((unsigned)lane, (unsigned)(1000 + lane));
  const int b4  = (lane >> 4) & 1;
  const int F16 = ((((int)pr16.x >= 1000) ? 1 : 0) ^ b4) ? 0 : 1;
  u32x2 pr32 = plswap32((unsigned)lane, (unsigned)(1000 + lane));
  const int b5  = (lane >> 5) & 1;
  const int F32 = ((((int)pr32.x >= 1000) ? 1 : 0) ^ b5) ? 0 : 1;

  // ---- weights: partial (j,k) carries column (lane&15)|((j^F16)<<4)|
  // ((k^F32)<<5) (r5-proven layout), rows permuted to gather order,
  // scaled by -2*SC (r-recurrence), pinned in VGPRs ----
  const int cb  = lane & 15;
  const int c00 = cb | ((0 ^ F16) << 4) | ((0 ^ F32) << 5);
  const int c01 = cb | ((0 ^ F16) << 4) | ((1 ^ F32) << 5);
  const int c10 = cb | ((1 ^ F16) << 4) | ((0 ^ F32) << 5);
  const int c11 = cb | ((1 ^ F16) << 4) | ((1 ^ F32) << 5);
  v2f w00[8], w01[8], w10[8], w11[8];
#pragma unroll
  for (int s = 0; s < 8; ++s) {
    const int i0 = gcal[2 * s] * UNITS, i1 = gcal[2 * s + 1] * UNITS;
    float t00 = -2.f * SC * Whh[i0 + c00], t01 = -2.f * SC * Whh[i1 + c00];
    float t10 = -2.f * SC * Whh[i0 + c01], t11 = -2.f * SC * Whh[i1 + c01];
    float t20 = -2.f * SC * Whh[i0 + c10], t21 = -2.f * SC * Whh[i1 + c10];
    float t30 = -2.f * SC * Whh[i0 + c11], t31 = -2.f * SC * Whh[i1 + c11];
    asm volatile("" : "+v"(t00), "+v"(t01), "+v"(t10), "+v"(t11));
    asm volatile("" : "+v"(t20), "+v"(t21), "+v"(t30), "+v"(t31));
    w00[s].x = t00; w00[s].y = t01;  w01[s].x = t10; w01[s].y = t11;
    w10[s].x = t20; w10[s].y = t21;  w11[s].x = t30; w11[s].y = t31;
  }

  const int* trow = tok + (long)row * SEQ;

  float r = 0.5f;  // h = 0  <=>  r = 0.5

  // Uniform token ring (scalar loads): tkc = token(t+2) at iter t.
  int tkc = trow[2], tkn = trow[3];
  // P-value ring: a0 = row(t), a1 = row(t+1).
  float a0 = P[(long)trow[0] * UNITS + lane];
  float a1 = P[(long)trow[1] * UNITS + lane];

#pragma unroll 8
  for (int t = 0; t < SEQ; ++t) {
    float a_cur = a0;
    a0 = a1;
    a1 = P[(long)tkc * UNITS + lane];   // row t+2 (dist-2: latency covered)
    const int nidx = (t + 4 < SEQ) ? t + 4 : SEQ - 1;  // uniform clamp
    tkc = tkn; tkn = trow[nidx];

    // ---- in-register all-gather of r across own 16-lane row ----
    int gi[16];
    GATHER_ROW(__float_as_int(r), gi);

    // ---- 4 parity-assigned partials, A/B-split accumulators:
    // 8 chains x 4-deep + 1 pk_add merge (fma-block links 9 -> 6) ----
    v2f q00A = {0.f, 0.f}, q01A = {0.f, 0.f}, q10A = {0.f, 0.f}, q11A = {0.f, 0.f};
    v2f q00B = {0.f, 0.f}, q01B = {0.f, 0.f}, q10B = {0.f, 0.f}, q11B = {0.f, 0.f};
#pragma unroll
    for (int s = 0; s < 8; ++s) {
      v2f gp;
      gp.x = __int_as_float(gi[2 * s]);
      gp.y = __int_as_float(gi[2 * s + 1]);
      if (s & 1) {
        q00B += gp * w00[s];
        q01B += gp * w01[s];
        q10B += gp * w10[s];
        q11B += gp * w11[s];
      } else {
        q00A += gp * w00[s];
        q01A += gp * w01[s];
        q10A += gp * w10[s];
        q11A += gp * w11[s];
      }
    }
    v2f r00 = q00A + q00B, r01 = q01A + q01B;
    v2f r10 = q10A + q10B, r11 = q11A + q11B;
    float p00 = r00.x + r00.y;   // partial (j=0,k=0)
    float p01 = r01.x + r01.y;   // partial (j=0,k=1)
    float p10 = r10.x + r10.y;   // partial (j=1,k=0)
    float p11 = r11.x + r11.y;   // partial (j=1,k=1)

    // ---- selection-free combine (vdst slot = j/k = 1), then fold the
    // precomputed input term a (own column) once at the end ----
    float g0 = swadd16(p10, p00);        // halfsum, col bit5 = 0^F32
    float g1 = swadd16(p11, p01);        // halfsum, col bit5 = 1^F32
    float yv = swadd32(g1, g0) + a_cur;  // = SC * 2s(t+1)

    // r = 1/(e^{2s}+1);  e^{2s} = 2^yv (SC prescale)
    r = __builtin_amdgcn_rcpf(__builtin_amdgcn_exp2f(yv) + 1.f);
  }

  // h = 1 - 2r (once); out[row] = sigmoid(sum_j h[j]*Wout[j] + bout)
  float h = __builtin_fmaf(-2.f, r, 1.f);
  float p = h * Wout[lane];
#pragma unroll
  for (int off = 32; off > 0; off >>= 1) p += __shfl_xor(p, off);
  if (lane == 0) out[row] = 1.f / (1.f + __expf(-(p + bout[0])));
}

extern "C" void kernel_launch(void* const* d_in, const int* in_sizes, int n_in,
                              void* d_out, int out_size, void* d_ws, size_t ws_size,
                              hipStream_t stream) {
  const int*   tok  = (const int*)  d_in[0];  // [BATCH, SEQ] int32
  const float* emb  = (const float*)d_in[1];  // [VOCAB, EMB]
  const float* Wxh  = (const float*)d_in[2];  // [EMB, UNITS]
  const float* Whh  = (const float*)d_in[3];  // [UNITS, UNITS]
  const float* bias = (const float*)d_in[4];  // [UNITS]
  const float* Wout = (const float*)d_in[5];  // [UNITS, 1]
  const float* bout = (const float*)d_in[6];  // [1]
  float* out = (float*)d_out;                 // [BATCH, 1] fp32

  float* P = (float*)d_ws;                    // VOCAB*UNITS fp32 = 256 KB

  proj_kernel<<<VOCAB, 64, 0, stream>>>(emb, Wxh, bias, Whh, P);
  scan_kernel<<<BATCH, 64, 0, stream>>>(tok, P, Whh, Wout, bout, out);
}

// Round 12
// 92.843 us; speedup vs baseline: 1.0330x; 1.0330x over previous
//
#include <hip/hip_runtime.h>

#define BATCH 512
#define SEQ   512
#define VOCAB 1000
#define EMB   100
#define UNITS 64
#define SC    2.88539008177792681f   // 2*log2(e): exp2(SC*s) == e^{2s}

typedef float    v2f   __attribute__((ext_vector_type(2)));
typedef unsigned u32x2 __attribute__((ext_vector_type(2)));

// ---------------------------------------------------------------------------
// Kernel 1: P[v][u] = SC*( (emb[v]@Wxh)[u] + b[u] + colsum(Whh)[u] )
// colsum fold supports the r-recurrence: y = x + W.h, h = 1-2r
//   =>  y = (x + W.1) - 2*W.r  -- no per-step h reconstruction in the scan.
// ---------------------------------------------------------------------------
__global__ __launch_bounds__(64) void proj_kernel(
    const float* __restrict__ emb, const float* __restrict__ Wxh,
    const float* __restrict__ bias, const float* __restrict__ Whh,
    float* __restrict__ P) {
  const int v = blockIdx.x;
  const int u = threadIdx.x;
  const float* e = emb + v * EMB;
  float acc = bias[u];
#pragma unroll 5
  for (int d = 0; d < EMB; ++d) acc += e[d] * Wxh[d * UNITS + u];
  float csum = 0.f;
#pragma unroll 8
  for (int i = 0; i < UNITS; ++i) csum += Whh[i * UNITS + u];
  P[v * UNITS + u] = SC * (acc + csum);
}

// ---------------------------------------------------------------------------
// DPP all-gather across the lane's own 16-lane row; slot->source permutation
// calibrated at runtime on lane_id and folded into the weight layout.
// ---------------------------------------------------------------------------
#define DPP_I(src, ctrl) __builtin_amdgcn_update_dpp(0, (src), (ctrl), 0xF, 0xF, true)

#define GATHER_ROW(v_, g_)                                          \
  do {                                                              \
    g_[0] = DPP_I((v_), 0x00);  g_[1] = DPP_I((v_), 0x55);          \
    g_[2] = DPP_I((v_), 0xAA);  g_[3] = DPP_I((v_), 0xFF);          \
    g_[4]  = DPP_I(g_[0], 0x124); g_[5]  = DPP_I(g_[1], 0x124);     \
    g_[6]  = DPP_I(g_[2], 0x124); g_[7]  = DPP_I(g_[3], 0x124);     \
    g_[8]  = DPP_I(g_[0], 0x128); g_[9]  = DPP_I(g_[1], 0x128);     \
    g_[10] = DPP_I(g_[2], 0x128); g_[11] = DPP_I(g_[3], 0x128);     \
    g_[12] = DPP_I(g_[0], 0x12C); g_[13] = DPP_I(g_[1], 0x12C);     \
    g_[14] = DPP_I(g_[2], 0x12C); g_[15] = DPP_I(g_[3], 0x12C);     \
  } while (0)

// Raw permlane swap returning BOTH outputs. Builtin path (scheduler-managed
// hazards, no volatile fence); fallback = r5-proven non-volatile asm.
#if __has_builtin(__builtin_amdgcn_permlane16_swap) && \
    __has_builtin(__builtin_amdgcn_permlane32_swap)
__device__ __forceinline__ u32x2 plswap16(unsigned x, unsigned y) {
  return __builtin_amdgcn_permlane16_swap(x, y, false, false);
}
__device__ __forceinline__ u32x2 plswap32(unsigned x, unsigned y) {
  return __builtin_amdgcn_permlane32_swap(x, y, false, false);
}
#else
__device__ __forceinline__ u32x2 plswap16(unsigned x, unsigned y) {
  asm("s_nop 1\n\tv_permlane16_swap_b32 %0, %1" : "+v"(x), "+v"(y));
  u32x2 r; r.x = x; r.y = y; return r;
}
__device__ __forceinline__ u32x2 plswap32(unsigned x, unsigned y) {
  asm("s_nop 1\n\tv_permlane32_swap_b32 %0, %1" : "+v"(x), "+v"(y));
  u32x2 r; r.x = x; r.y = y; return r;
}
#endif

// Selection-free combine (r5/r10-proven algebra): sum of both swap outputs =
// q_w[l] + q_w[l^N], with the "winning" partial w alternating by lane
// parity -- absorbed into the calibrated weight-column layout below.
__device__ __forceinline__ float swadd16(float vd, float vs) {
  u32x2 p = plswap16((unsigned)__float_as_int(vd), (unsigned)__float_as_int(vs));
  return __int_as_float((int)p.x) + __int_as_float((int)p.y);
}
__device__ __forceinline__ float swadd32(float vd, float vs) {
  u32x2 p = plswap32((unsigned)__float_as_int(vd), (unsigned)__float_as_int(vs));
  return __int_as_float((int)p.x) + __int_as_float((int)p.y);
}

// ---------------------------------------------------------------------------
// Kernel 2: sequential scan on r(t) = 1/(e^{2s}+1), one row per wave.
// Regime (r2/r10/r11-calibrated): lone-wave issue cadence ~5.3 cyc/instr --
// timing tracks TOTAL instruction count (VALU+SALU+SMEM), not chain depth.
// Math body = r10 verbatim (best: 94.3us, the p=4/g=16 decomposition is the
// 62-op floor). This round removes the per-step token SALU overhead: tokens
// come in 16-wide SGPR blocks (s_load_dwordx16-mergeable burst per chunk,
// ping-pong buffered, inner 16 fully unrolled so every token index is a
// compile-time SGPR reference) -- no ring movs, no tail clamp per step.
// ---------------------------------------------------------------------------
__global__ __launch_bounds__(64)
__attribute__((amdgpu_waves_per_eu(1, 1)))
void scan_kernel(
    const int* __restrict__ tok, const float* __restrict__ P,
    const float* __restrict__ Whh, const float* __restrict__ Wout,
    const float* __restrict__ bout, float* __restrict__ out) {
  const int row  = blockIdx.x;
  const int lane = threadIdx.x;

  // ---- calibration: gather permutation ----
  int gcal[16];
  GATHER_ROW(lane, gcal);  // gcal[s] = source lane (== unit index) of slot s

  // ---- calibration: swap convention flags F16/F32 (r5-proven probe) ----
  u32x2 pr16 = plswap16((unsigned)lane, (unsigned)(1000 + lane));
  const int b4  = (lane >> 4) & 1;
  const int F16 = ((((int)pr16.x >= 1000) ? 1 : 0) ^ b4) ? 0 : 1;
  u32x2 pr32 = plswap32((unsigned)lane, (unsigned)(1000 + lane));
  const int b5  = (lane >> 5) & 1;
  const int F32 = ((((int)pr32.x >= 1000) ? 1 : 0) ^ b5) ? 0 : 1;

  // ---- weights: partial (j,k) carries column (lane&15)|((j^F16)<<4)|
  // ((k^F32)<<5) (r5-proven layout), rows permuted to gather order,
  // scaled by -2*SC (r-recurrence), pinned in VGPRs ----
  const int cb  = lane & 15;
  const int c00 = cb | ((0 ^ F16) << 4) | ((0 ^ F32) << 5);
  const int c01 = cb | ((0 ^ F16) << 4) | ((1 ^ F32) << 5);
  const int c10 = cb | ((1 ^ F16) << 4) | ((0 ^ F32) << 5);
  const int c11 = cb | ((1 ^ F16) << 4) | ((1 ^ F32) << 5);
  v2f w00[8], w01[8], w10[8], w11[8];
#pragma unroll
  for (int s = 0; s < 8; ++s) {
    const int i0 = gcal[2 * s] * UNITS, i1 = gcal[2 * s + 1] * UNITS;
    float t00 = -2.f * SC * Whh[i0 + c00], t01 = -2.f * SC * Whh[i1 + c00];
    float t10 = -2.f * SC * Whh[i0 + c01], t11 = -2.f * SC * Whh[i1 + c01];
    float t20 = -2.f * SC * Whh[i0 + c10], t21 = -2.f * SC * Whh[i1 + c10];
    float t30 = -2.f * SC * Whh[i0 + c11], t31 = -2.f * SC * Whh[i1 + c11];
    asm volatile("" : "+v"(t00), "+v"(t01), "+v"(t10), "+v"(t11));
    asm volatile("" : "+v"(t20), "+v"(t21), "+v"(t30), "+v"(t31));
    w00[s].x = t00; w00[s].y = t01;  w01[s].x = t10; w01[s].y = t11;
    w10[s].x = t20; w10[s].y = t21;  w11[s].x = t30; w11[s].y = t31;
  }

  const int* trow = tok + (long)row * SEQ;

  float r = 0.5f;  // h = 0  <=>  r = 0.5

  // ---- one scan step (r10 math body, verbatim) ----
#define STEP(TOKPF)                                                        \
  do {                                                                     \
    float a_cur = a0;                                                      \
    a0 = a1;                                                               \
    a1 = P[(long)(TOKPF) * UNITS + lane]; /* row t+2, dist-2 prefetch */   \
    int gi[16];                                                            \
    GATHER_ROW(__float_as_int(r), gi);                                     \
    v2f q00 = {0.f, 0.f}, q01 = {0.f, 0.f};                                \
    v2f q10 = {0.f, 0.f}, q11 = {0.f, 0.f};                                \
    _Pragma("unroll")                                                      \
    for (int s = 0; s < 8; ++s) {                                          \
      v2f gp;                                                              \
      gp.x = __int_as_float(gi[2 * s]);                                    \
      gp.y = __int_as_float(gi[2 * s + 1]);                                \
      q00 += gp * w00[s];                                                  \
      q01 += gp * w01[s];                                                  \
      q10 += gp * w10[s];                                                  \
      q11 += gp * w11[s];                                                  \
    }                                                                      \
    float p00 = q00.x + q00.y;                                             \
    float p01 = q01.x + q01.y;                                             \
    float p10 = q10.x + q10.y;                                             \
    float p11 = q11.x + q11.y;                                             \
    float g0 = swadd16(p10, p00);                                          \
    float g1 = swadd16(p11, p01);                                          \
    float yv = swadd32(g1, g0) + a_cur;                                    \
    r = __builtin_amdgcn_rcpf(__builtin_amdgcn_exp2f(yv) + 1.f);           \
  } while (0)

  // Token SGPR blocks, ping-pong: tka = current chunk's 16 tokens,
  // other buffer prefetched while processing. All indices compile-time.
  int tka[16], tkb[16];
#pragma unroll
  for (int i = 0; i < 16; ++i) tka[i] = trow[i];

  // P-value ring: a0 = row(t), a1 = row(t+1).
  float a0 = P[(long)tka[0] * UNITS + lane];
  float a1 = P[(long)tka[1] * UNITS + lane];

  for (int c = 0; c < SEQ / 16; c += 2) {
    // chunk c (tokens in tka); prefetch chunk c+1 into tkb
#pragma unroll
    for (int i = 0; i < 16; ++i) tkb[i] = trow[(c + 1) * 16 + i];
#pragma unroll
    for (int i = 0; i < 16; ++i) {
      STEP(i < 14 ? tka[i + 2] : tkb[i - 14]);
    }
    // chunk c+1 (tokens in tkb); prefetch chunk c+2 into tka
    // (at the last pair c+2 == 32: load dummy in-range token 511 --
    //  those prefetched P rows are never consumed)
    const int nb = (c + 2 < SEQ / 16) ? (c + 2) * 16 : SEQ - 1;
    const int st = (c + 2 < SEQ / 16) ? 1 : 0;
#pragma unroll
    for (int i = 0; i < 16; ++i) tka[i] = trow[nb + st * i];
#pragma unroll
    for (int i = 0; i < 16; ++i) {
      STEP(i < 14 ? tkb[i + 2] : tka[i - 14]);
    }
  }
#undef STEP

  // h = 1 - 2r (once); out[row] = sigmoid(sum_j h[j]*Wout[j] + bout)
  float h = __builtin_fmaf(-2.f, r, 1.f);
  float p = h * Wout[lane];
#pragma unroll
  for (int off = 32; off > 0; off >>= 1) p += __shfl_xor(p, off);
  if (lane == 0) out[row] = 1.f / (1.f + __expf(-(p + bout[0])));
}

extern "C" void kernel_launch(void* const* d_in, const int* in_sizes, int n_in,
                              void* d_out, int out_size, void* d_ws, size_t ws_size,
                              hipStream_t stream) {
  const int*   tok  = (const int*)  d_in[0];  // [BATCH, SEQ] int32
  const float* emb  = (const float*)d_in[1];  // [VOCAB, EMB]
  const float* Wxh  = (const float*)d_in[2];  // [EMB, UNITS]
  const float* Whh  = (const float*)d_in[3];  // [UNITS, UNITS]
  const float* bias = (const float*)d_in[4];  // [UNITS]
  const float* Wout = (const float*)d_in[5];  // [UNITS, 1]
  const float* bout = (const float*)d_in[6];  // [1]
  float* out = (float*)d_out;                 // [BATCH, 1] fp32

  float* P = (float*)d_ws;                    // VOCAB*UNITS fp32 = 256 KB

  proj_kernel<<<VOCAB, 64, 0, stream>>>(emb, Wxh, bias, Whh, P);
  scan_kernel<<<BATCH, 64, 0, stream>>>(tok, P, Whh, Wout, bout, out);
}

// Round 14
// 83.098 us; speedup vs baseline: 1.1542x; 1.1173x over previous
//
#include <hip/hip_runtime.h>

#define BATCH 512
#define SEQ   512
#define VOCAB 1000
#define EMB   100
#define UNITS 64
#define SC    2.88539008177792681f   // 2*log2(e): exp2(SC*s) == e^{2s}

typedef float     v2f   __attribute__((ext_vector_type(2)));
typedef unsigned  u32x2 __attribute__((ext_vector_type(2)));
typedef _Float16  h2    __attribute__((ext_vector_type(2)));

// ---------------------------------------------------------------------------
// Kernel 1: P[v][u] = SC*( (emb[v]@Wxh)[u] + b[u] + colsum(Whh)[u] )
// (r6-proven colsum fold for the r-recurrence; P stays fp32.)
// ---------------------------------------------------------------------------
__global__ __launch_bounds__(64) void proj_kernel(
    const float* __restrict__ emb, const float* __restrict__ Wxh,
    const float* __restrict__ bias, const float* __restrict__ Whh,
    float* __restrict__ P) {
  const int v = blockIdx.x;
  const int u = threadIdx.x;
  const float* e = emb + v * EMB;
  float acc = bias[u];
#pragma unroll 5
  for (int d = 0; d < EMB; ++d) acc += e[d] * Wxh[d * UNITS + u];
  float csum = 0.f;
#pragma unroll 8
  for (int i = 0; i < UNITS; ++i) csum += Whh[i * UNITS + u];
  P[v * UNITS + u] = SC * (acc + csum);
}

// ---------------------------------------------------------------------------
// DPP machinery. GATHER8: all-gather of the lane's own 16-lane row as 8
// PACKED f16x2 registers (sources = the row's 8 even lanes, which hold
// (r[e], r[e+1]) after the pack step). Slot->source permutation calibrated
// at runtime on lane_id and folded into the f16 weight-pair layout.
// ---------------------------------------------------------------------------
#define DPP_I(src, ctrl) __builtin_amdgcn_update_dpp(0, (src), (ctrl), 0xF, 0xF, true)

#define GATHER8(v_, g_)                                             \
  do {                                                              \
    g_[0] = DPP_I((v_), 0x00);   /* quad_perm:[0,0,0,0] */          \
    g_[1] = DPP_I((v_), 0xAA);   /* quad_perm:[2,2,2,2] */          \
    g_[2] = DPP_I(g_[0], 0x124); g_[3] = DPP_I(g_[1], 0x124);       \
    g_[4] = DPP_I(g_[0], 0x128); g_[5] = DPP_I(g_[1], 0x128);       \
    g_[6] = DPP_I(g_[0], 0x12C); g_[7] = DPP_I(g_[1], 0x12C);       \
  } while (0)

// Raw permlane swap returning BOTH outputs (r10-proven).
#if __has_builtin(__builtin_amdgcn_permlane16_swap) && \
    __has_builtin(__builtin_amdgcn_permlane32_swap)
__device__ __forceinline__ u32x2 plswap16(unsigned x, unsigned y) {
  return __builtin_amdgcn_permlane16_swap(x, y, false, false);
}
__device__ __forceinline__ u32x2 plswap32(unsigned x, unsigned y) {
  return __builtin_amdgcn_permlane32_swap(x, y, false, false);
}
#else
__device__ __forceinline__ u32x2 plswap16(unsigned x, unsigned y) {
  asm("s_nop 1\n\tv_permlane16_swap_b32 %0, %1" : "+v"(x), "+v"(y));
  u32x2 r; r.x = x; r.y = y; return r;
}
__device__ __forceinline__ u32x2 plswap32(unsigned x, unsigned y) {
  asm("s_nop 1\n\tv_permlane32_swap_b32 %0, %1" : "+v"(x), "+v"(y));
  u32x2 r; r.x = x; r.y = y; return r;
}
#endif

// Selection-free combine (r5/r10-proven algebra).
__device__ __forceinline__ float swadd16(float vd, float vs) {
  u32x2 p = plswap16((unsigned)__float_as_int(vd), (unsigned)__float_as_int(vs));
  return __int_as_float((int)p.x) + __int_as_float((int)p.y);
}
__device__ __forceinline__ float swadd32(float vd, float vs) {
  u32x2 p = plswap32((unsigned)__float_as_int(vd), (unsigned)__float_as_int(vs));
  return __int_as_float((int)p.x) + __int_as_float((int)p.y);
}

// f16 pair dot with f32 accumulate: v_dot2_f32_f16 (2 MACs + horiz add).
__device__ __forceinline__ float dot2(int a, int b, float c) {
#if __has_builtin(__builtin_amdgcn_fdot2)
  return __builtin_amdgcn_fdot2(__builtin_bit_cast(h2, a),
                                __builtin_bit_cast(h2, b), c, false);
#else  // compile-insurance fallback (slow, same numerics class)
  h2 ha = __builtin_bit_cast(h2, a), hb = __builtin_bit_cast(h2, b);
  return c + (float)ha.x * (float)hb.x + (float)ha.y * (float)hb.y;
#endif
}

// ---------------------------------------------------------------------------
// Kernel 2: sequential scan on r(t) = 1/(e^{2s}+1), one row per wave.
// Slot model (r2..r12-calibrated): step = ~5.3-6.2 cyc per ISSUE SLOT; the
// fp32 body was at its 62-VALU floor. This round: matvec inputs in f16
// (weights pre-converted f16 pairs; h packed per step via 1 DPP + cvt_pkrtz),
// v_dot2_f32_f16 keeps f32 accumulation. Gather 16 DPP -> 8; extracts 4 -> 0.
// Per step: pack(2) + gather(8) + 32 dot2 + combine(6) + a-fold(1) +
// exp2/add/rcp(3) + P load(~4). Combine/recurrence/token flow = r12 verbatim.
// ---------------------------------------------------------------------------
__global__ __launch_bounds__(64)
__attribute__((amdgpu_waves_per_eu(1, 1)))
void scan_kernel(
    const int* __restrict__ tok, const float* __restrict__ P,
    const float* __restrict__ Whh, const float* __restrict__ Wout,
    const float* __restrict__ bout, float* __restrict__ out) {
  const int row  = blockIdx.x;
  const int lane = threadIdx.x;

  // ---- calibration: pair-gather permutation (slot s -> even source lane) --
  int g2cal[8];
  GATHER8(lane, g2cal);  // g2cal[s] = e_s (even unit index; pair = e_s, e_s+1)

  // ---- calibration: swap convention flags F16/F32 (r5/r10-proven probe) ---
  u32x2 pr16 = plswap16((unsigned)lane, (unsigned)(1000 + lane));
  const int b4  = (lane >> 4) & 1;
  const int F16 = ((((int)pr16.x >= 1000) ? 1 : 0) ^ b4) ? 0 : 1;
  u32x2 pr32 = plswap32((unsigned)lane, (unsigned)(1000 + lane));
  const int b5  = (lane >> 5) & 1;
  const int F32 = ((((int)pr32.x >= 1000) ? 1 : 0) ^ b5) ? 0 : 1;

  // ---- weights: partial (j,k) carries column (lane&15)|((j^F16)<<4)|
  // ((k^F32)<<5); pair-slots permuted to gather order; scaled by -2*SC;
  // converted RNE to f16 pairs; pinned in VGPRs (32 regs total) ----
  const int cb  = lane & 15;
  const int c00 = cb | ((0 ^ F16) << 4) | ((0 ^ F32) << 5);
  const int c01 = cb | ((0 ^ F16) << 4) | ((1 ^ F32) << 5);
  const int c10 = cb | ((1 ^ F16) << 4) | ((0 ^ F32) << 5);
  const int c11 = cb | ((1 ^ F16) << 4) | ((1 ^ F32) << 5);
  int w00[8], w01[8], w10[8], w11[8];
#pragma unroll
  for (int s = 0; s < 8; ++s) {
    const long i0 = (long)g2cal[s] * UNITS;       // unit e_s
    const long i1 = i0 + UNITS;                   // unit e_s + 1
    h2 t00, t01, t10, t11;
    t00.x = (_Float16)(-2.f * SC * Whh[i0 + c00]);
    t00.y = (_Float16)(-2.f * SC * Whh[i1 + c00]);
    t01.x = (_Float16)(-2.f * SC * Whh[i0 + c01]);
    t01.y = (_Float16)(-2.f * SC * Whh[i1 + c01]);
    t10.x = (_Float16)(-2.f * SC * Whh[i0 + c10]);
    t10.y = (_Float16)(-2.f * SC * Whh[i1 + c10]);
    t11.x = (_Float16)(-2.f * SC * Whh[i0 + c11]);
    t11.y = (_Float16)(-2.f * SC * Whh[i1 + c11]);
    int u0 = __builtin_bit_cast(int, t00), u1 = __builtin_bit_cast(int, t01);
    int u2 = __builtin_bit_cast(int, t10), u3 = __builtin_bit_cast(int, t11);
    asm volatile("" : "+v"(u0), "+v"(u1), "+v"(u2), "+v"(u3));
    w00[s] = u0; w01[s] = u1; w10[s] = u2; w11[s] = u3;
  }

  const int* trow = tok + (long)row * SEQ;

  float r = 0.5f;  // h = 0  <=>  r = 0.5

  // ---- one scan step ----
#define STEP(TOKPF)                                                        \
  do {                                                                     \
    float a_cur = a0;                                                      \
    a0 = a1;                                                               \
    a1 = P[(long)(TOKPF) * UNITS + lane]; /* row t+2, dist-2 prefetch */   \
    /* pack (r[e], r[e+1]) into even lanes: qp[1,1,3,3] + cvt_pkrtz */     \
    int nbi = DPP_I(__float_as_int(r), 0xF5);                              \
    int pki = __builtin_bit_cast(                                          \
        int, __builtin_amdgcn_cvt_pkrtz(r, __int_as_float(nbi)));          \
    int gp2[8];                                                            \
    GATHER8(pki, gp2);                                                     \
    float q00 = 0.f, q01 = 0.f, q10 = 0.f, q11 = 0.f;                      \
    _Pragma("unroll")                                                      \
    for (int s = 0; s < 8; ++s) {                                          \
      q00 = dot2(gp2[s], w00[s], q00);                                     \
      q01 = dot2(gp2[s], w01[s], q01);                                     \
      q10 = dot2(gp2[s], w10[s], q10);                                     \
      q11 = dot2(gp2[s], w11[s], q11);                                     \
    }                                                                      \
    float g0 = swadd16(q10, q00);                                          \
    float g1 = swadd16(q11, q01);                                          \
    float yv = swadd32(g1, g0) + a_cur;                                    \
    r = __builtin_amdgcn_rcpf(__builtin_amdgcn_exp2f(yv) + 1.f);           \
  } while (0)

  // Token SGPR blocks, ping-pong (r12-proven): all indices compile-time.
  int tka[16], tkb[16];
#pragma unroll
  for (int i = 0; i < 16; ++i) tka[i] = trow[i];

  // P-value ring: a0 = row(t), a1 = row(t+1).
  float a0 = P[(long)tka[0] * UNITS + lane];
  float a1 = P[(long)tka[1] * UNITS + lane];

  for (int c = 0; c < SEQ / 16; c += 2) {
#pragma unroll
    for (int i = 0; i < 16; ++i) tkb[i] = trow[(c + 1) * 16 + i];
#pragma unroll
    for (int i = 0; i < 16; ++i) {
      STEP(i < 14 ? tka[i + 2] : tkb[i - 14]);
    }
    const int nb = (c + 2 < SEQ / 16) ? (c + 2) * 16 : SEQ - 1;
    const int st = (c + 2 < SEQ / 16) ? 1 : 0;
#pragma unroll
    for (int i = 0; i < 16; ++i) tka[i] = trow[nb + st * i];
#pragma unroll
    for (int i = 0; i < 16; ++i) {
      STEP(i < 14 ? tkb[i + 2] : tka[i - 14]);
    }
  }
#undef STEP

  // h = 1 - 2r (once, fp32); out[row] = sigmoid(sum_j h[j]*Wout[j] + bout)
  float h = __builtin_fmaf(-2.f, r, 1.f);
  float p = h * Wout[lane];
#pragma unroll
  for (int off = 32; off > 0; off >>= 1) p += __shfl_xor(p, off);
  if (lane == 0) out[row] = 1.f / (1.f + __expf(-(p + bout[0])));
}

extern "C" void kernel_launch(void* const* d_in, const int* in_sizes, int n_in,
                              void* d_out, int out_size, void* d_ws, size_t ws_size,
                              hipStream_t stream) {
  const int*   tok  = (const int*)  d_in[0];  // [BATCH, SEQ] int32
  const float* emb  = (const float*)d_in[1];  // [VOCAB, EMB]
  const float* Wxh  = (const float*)d_in[2];  // [EMB, UNITS]
  const float* Whh  = (const float*)d_in[3];  // [UNITS, UNITS]
  const float* bias = (const float*)d_in[4];  // [UNITS]
  const float* Wout = (const float*)d_in[5];  // [UNITS, 1]
  const float* bout = (const float*)d_in[6];  // [1]
  float* out = (float*)d_out;                 // [BATCH, 1] fp32

  float* P = (float*)d_ws;                    // VOCAB*UNITS fp32 = 256 KB

  proj_kernel<<<VOCAB, 64, 0, stream>>>(emb, Wxh, bias, Whh, P);
  scan_kernel<<<BATCH, 64, 0, stream>>>(tok, P, Whh, Wout, bout, out);
}